// Round 2
// baseline (173.996 us; speedup 1.0000x reference)
//
#include <hip/hip_runtime.h>
#include <stdint.h>

#define NB 4      // batch
#define SEQ 1024  // sequence
#define DM 256    // d_model == head_dim
#define NH 8      // heads

typedef __attribute__((ext_vector_type(8))) short bf8;   // 8 bf16 (4 VGPRs)
typedef __attribute__((ext_vector_type(4))) float f4;    // MFMA accumulator

__device__ __forceinline__ unsigned short f2bf(float f) {
  union { float f; uint32_t u; } c; c.f = f;
  uint32_t u = c.u;
  return (unsigned short)((u + 0x7FFFu + ((u >> 16) & 1u)) >> 16); // RNE
}

// async global->LDS DMA, 16B per lane (m97 recipe): lds dst = base + lane*16.
__device__ __forceinline__ void gl_lds16(const unsigned short* g, short* l) {
  __builtin_amdgcn_global_load_lds(
      (const __attribute__((address_space(1))) unsigned int*)g,
      (__attribute__((address_space(3))) unsigned int*)l, 16, 0, 0);
}

// Fragment-major layouts (per bh slice = 262144 elems = 512 KB):
//  q_frag/k_frag: [tile16 (token/16)][dchunk (d/32)][lane64][j8]
//  v_frag:        [dtile (d/16)][kvchunk (kv/32)][lane64][j8]

// ---------------------------------------------------------------------------
// Kernel 0: ALL prep in one launch.  grid (1024, 7), 256 thr.  (unchanged)
// ---------------------------------------------------------------------------
__global__ __launch_bounds__(256) void prep_kernel(
    const float* __restrict__ Wq, const float* __restrict__ Wk,
    const float* __restrict__ Wv, const float* __restrict__ Wo,
    const float* __restrict__ Q, const float* __restrict__ K,
    const float* __restrict__ V,
    unsigned short* __restrict__ Wt3, unsigned short* __restrict__ WoT,
    unsigned short* __restrict__ Xbf) {
  const int z = blockIdx.y;
  const int tid = threadIdx.x;
  if (z >= 4) {
    const float* src = (z == 4) ? Q : (z == 5) ? K : V;
    const size_t off = (size_t)blockIdx.x * 1024 + tid * 4;
    const float4 v = *(const float4*)(src + off);
    short4 s;
    s.x = (short)f2bf(v.x); s.y = (short)f2bf(v.y);
    s.z = (short)f2bf(v.z); s.w = (short)f2bf(v.w);
    *(short4*)(Xbf + (size_t)(z - 4) * 4096 * 256 + off) = s;
    return;
  }
  if (blockIdx.x >= 512) return;
  const float* in;
  unsigned short* out;
  int R, C, bx, by;
  if (z < 3) {
    in = (z == 0) ? Wq : (z == 1) ? Wk : Wv;
    out = Wt3 + (size_t)z * 2048 * 256;
    R = 256; C = 2048; bx = blockIdx.x & 63; by = blockIdx.x >> 6;
  } else {
    in = Wo; out = WoT;
    R = 2048; C = 256; bx = blockIdx.x & 7; by = blockIdx.x >> 3;
  }
  __shared__ float t[32][33];
  const int c0 = bx * 32, r0 = by * 32;
  const int tx = tid & 31, ty = tid >> 5;
#pragma unroll
  for (int i = 0; i < 4; i++) {
    int r = r0 + ty + i * 8;
    t[ty + i * 8][tx] = in[(size_t)r * C + c0 + tx];
  }
  __syncthreads();
#pragma unroll
  for (int i = 0; i < 4; i++) {
    int c = c0 + ty + i * 8;
    out[(size_t)c * R + r0 + tx] = f2bf(t[tx][ty + i * 8]);
  }
}

// ---------------------------------------------------------------------------
// Kernel 1: QKV projection GEMM (unchanged)
// ---------------------------------------------------------------------------
__global__ __launch_bounds__(256) void proj_kernel(
    const unsigned short* __restrict__ Xbf, const unsigned short* __restrict__ Wt3,
    const float* __restrict__ bq, const float* __restrict__ bk, const float* __restrict__ bv,
    unsigned short* __restrict__ q_frag, unsigned short* __restrict__ k_frag,
    unsigned short* __restrict__ v_frag) {
  const int z = blockIdx.z;
  const unsigned short* X = Xbf + (size_t)z * 4096 * 256;
  const unsigned short* Wt = Wt3 + (size_t)z * 2048 * 256;
  const float* bias = (z == 0) ? bq : (z == 1) ? bk : bv;

  __shared__ short a_lds[128 * 32];
  __shared__ short b_lds[128 * 32];

  const int tid = threadIdx.x;
  const int wid = tid >> 6, lane = tid & 63;
  const int quad = lane >> 4, l16 = lane & 15;
  const int wm = wid >> 1, wn = wid & 1;
  const int m0 = blockIdx.x * 128, n0 = blockIdx.y * 128;

  f4 acc[4][4];
  const f4 z4 = {0.f, 0.f, 0.f, 0.f};
#pragma unroll
  for (int i = 0; i < 4; i++)
#pragma unroll
    for (int j = 0; j < 4; j++) acc[i][j] = z4;

  const int srow = lane >> 2;
  const int schunk = lane & 3;
  const int cxor = quad ^ (l16 & 3);

  for (int ko = 0; ko < 8; ko++) {
    const int k0 = ko * 32;
#pragma unroll
    for (int j = 0; j < 2; j++) {
      const int i = wid * 2 + j;
      const int row = i * 16 + srow;
      const int sc = (schunk ^ (row & 3)) * 8;
      gl_lds16(X + (size_t)(m0 + row) * DM + k0 + sc, a_lds + i * 512);
      gl_lds16(Wt + (size_t)(n0 + row) * DM + k0 + sc, b_lds + i * 512);
    }
    __syncthreads();
    bf8 af[4], bfv[4];
#pragma unroll
    for (int mi = 0; mi < 4; mi++)
      af[mi] = *(const bf8*)(a_lds + (wm * 64 + mi * 16 + l16) * 32 + cxor * 8);
#pragma unroll
    for (int ni = 0; ni < 4; ni++)
      bfv[ni] = *(const bf8*)(b_lds + (wn * 64 + ni * 16 + l16) * 32 + cxor * 8);
    if (z < 2) {
#pragma unroll
      for (int ni = 0; ni < 4; ni++)
#pragma unroll
        for (int mi = 0; mi < 4; mi++)
          acc[ni][mi] = __builtin_amdgcn_mfma_f32_16x16x32_bf16(bfv[ni], af[mi], acc[ni][mi], 0, 0, 0);
    } else {
#pragma unroll
      for (int mi = 0; mi < 4; mi++)
#pragma unroll
        for (int ni = 0; ni < 4; ni++)
          acc[mi][ni] = __builtin_amdgcn_mfma_f32_16x16x32_bf16(af[mi], bfv[ni], acc[mi][ni], 0, 0, 0);
    }
    __syncthreads();
  }

  if (z < 2) {
    // q scale folds 1/sqrt(256) AND log2(e) (softmax uses exp2 directly)
    const float scale = (z == 0) ? 0.0901684400f : 1.0f;
    unsigned short* dst = (z == 0) ? q_frag : k_frag;
#pragma unroll
    for (int ni = 0; ni < 4; ni++) {
      const int nb = n0 + wn * 64 + ni * 16 + quad * 4;  // 4 consecutive d
      const float4 b4 = *(const float4*)(bias + nb);
      const int h = nb >> 8, dd = nb & 255;
      const int dq = (dd >> 3) & 3, jh = dd & 7;
#pragma unroll
      for (int mi = 0; mi < 4; mi++) {
        const int tok = m0 + wm * 64 + mi * 16 + l16;
        const int b = tok >> 10, sr = tok & 1023;
        const size_t idx = ((size_t)(b * NH + h) * 64 + (sr >> 4)) * 4096 +
                           (size_t)(dd >> 5) * 512 + ((sr & 15) + 16 * dq) * 8 + jh;
        short4 s4;
        s4.x = (short)f2bf((acc[ni][mi][0] + b4.x) * scale);
        s4.y = (short)f2bf((acc[ni][mi][1] + b4.y) * scale);
        s4.z = (short)f2bf((acc[ni][mi][2] + b4.z) * scale);
        s4.w = (short)f2bf((acc[ni][mi][3] + b4.w) * scale);
        *(short4*)(dst + idx) = s4;
      }
    }
  } else {
#pragma unroll
    for (int ni = 0; ni < 4; ni++) {
      const int n = n0 + wn * 64 + ni * 16 + l16;
      const float bsv = bias[n];
      const int h = n >> 8, d = n & 255;
#pragma unroll
      for (int mi = 0; mi < 4; mi++) {
        const int m = m0 + wm * 64 + mi * 16 + quad * 4;
        const int b = m >> 10, sr = m & 1023;
        const size_t idx = ((size_t)(b * NH + h) * 16 + (d >> 4)) * 16384 +
                           (size_t)(sr >> 5) * 512 +
                           ((d & 15) + 16 * ((sr >> 3) & 3)) * 8 + (sr & 7);
        short4 s4;
        s4.x = (short)f2bf(acc[mi][ni][0] + bsv);
        s4.y = (short)f2bf(acc[mi][ni][1] + bsv);
        s4.z = (short)f2bf(acc[mi][ni][2] + bsv);
        s4.w = (short)f2bf(acc[mi][ni][3] + bsv);
        *(short4*)(v_frag + idx) = s4;
      }
    }
  }
}

// ---------------------------------------------------------------------------
// Kernel 2: flash attention v14 = v12 schedule with the barrier DRAINS removed
// (T4 counted-wait protocol).  Evidence: v12 (1 bar/32kv) and v13 (2 bar/64kv,
// 40% less K-LDS read traffic) are both ~54us with identical counters; all
// pipes <30% busy -> the per-step `s_waitcnt vmcnt(0)` drain at every
// __syncthreads is the wall, not any throughput resource.
// Protocol: 3 rotating 16KB K buffers, prefetch depth 2.  Step t issues DMA
// K(t+2) (pinned at step top by sched_barrier), reads buf[t%3].  Per-wave
// vmem issue order is [K(t+1), vpre(t-1), K(t+2), vpre(t)]; the compiler's
// mandatory register-use wait for vpre(t-1) at PV (vmcnt<=4) retires K(t+1)
// BEFORE the wave signals the end-of-step barrier -> cross-wave LDS
// visibility for step t+1 with no explicit vmem drain.  Barrier = lgkmcnt(0)
// + raw s_barrier only (P-tile visibility).  Prologue stages K(0),K(1) and
// does one full __syncthreads to seed the invariant.
// S-phase: 4 independent MFMA chains (ILP).  LDS 59.6KB -> 2 blocks/CU.
// ---------------------------------------------------------------------------
__global__ __launch_bounds__(256, 2) void attn_kernel(
    const unsigned short* __restrict__ q_frag, const unsigned short* __restrict__ k_frag,
    const unsigned short* __restrict__ v_frag, unsigned short* __restrict__ o_ws) {
  __shared__ short k_lds[3 * 8192];   // 3 rotating 32kv x 256d K tiles
  __shared__ short p_lds[2][64][40];  // dbuf x (64 q x 32 kv), stride-40 banks
  __shared__ float l_sh[64];

  const int tid = threadIdx.x;
  const int wid = tid >> 6, lane = tid & 63;
  const int quad = lane >> 4, l16 = lane & 15;
  const int blk = blockIdx.x;
  const int g = blk & 7;                 // XCD (dispatch round-robin heuristic)
  const int qt = (blk >> 3) & 15;        // q tile (64 rows)
  const int bh = g + 8 * (blk >> 7);     // 16 same-bh blocks share one XCD
  const size_t fbase = (size_t)bh * 262144;

  // prologue DMA: K(0)->buf0, K(1)->buf1
  const unsigned short* kdma_src = k_frag + fbase + (size_t)wid * 2048 + lane * 8;
#pragma unroll
  for (int jj = 0; jj < 4; jj++) {
    gl_lds16(kdma_src + jj * 512, &k_lds[wid * 2048 + jj * 512]);
    gl_lds16(kdma_src + 8192 + jj * 512, &k_lds[8192 + wid * 2048 + jj * 512]);
  }

  // Q fragments: wave's own 16 q-rows, all 8 d-chunks (coalesced, once).
  bf8 qf[8];
  {
    const unsigned short* qp = q_frag + fbase + (size_t)(qt * 4 + wid) * 4096 + lane * 8;
#pragma unroll
    for (int kc = 0; kc < 8; kc++) qf[kc] = *(const bf8*)(qp + kc * 512);
  }

  const f4 z4 = {0.f, 0.f, 0.f, 0.f};
  f4 Oacc[4][4];  // [mi(d)][nq(q)]: d = wid*64+mi*16+quad*4+reg, q = nq*16+l16
#pragma unroll
  for (int i = 0; i < 4; i++)
#pragma unroll
    for (int j = 0; j < 4; j++) Oacc[i][j] = z4;
  float lpart[4] = {0.f, 0.f, 0.f, 0.f};

  __syncthreads();  // full drain ONCE: K(0),K(1) resident; invariant seeded

  bf8 vpre[4];  // wave's 64-d slice x 32 kv of V(t); single-buffered
  const unsigned short* vsrc = v_frag + fbase + (size_t)(wid * 4) * 16384 + lane * 8;
  short* const pB = &p_lds[0][0][0];

  int kRd = 0;          // byte-ish (short) offset of buf[t%3]
  int kPre = 2 * 8192;  // offset of buf[(t+2)%3]

#pragma unroll 1
  for (int t = 0; t < 32; ++t) {
    // [A] issue DMA K(t+2) -> buf[(t+2)%3]; MUST be oldest vmem of this step.
    if (t < 30) {
      const unsigned short* s0 = kdma_src + (size_t)(t + 2) * 8192;
#pragma unroll
      for (int jj = 0; jj < 4; jj++)
        gl_lds16(s0 + jj * 512, &k_lds[kPre + wid * 2048 + jj * 512]);
    }
    __builtin_amdgcn_sched_barrier(0);  // pin DMA issue order vs later vmem

    // [B] S = Q . K(t)^T : 16q x 32kv, 4 independent 8->4-deep chains
    f4 S0a = z4, S0b = z4, S1a = z4, S1b = z4;
#pragma unroll
    for (int cc = 0; cc < 4; cc++) {
      const bf8 k0a = *(const bf8*)(&k_lds[kRd + (2 * cc) * 512 + lane * 8]);
      const bf8 k0b = *(const bf8*)(&k_lds[kRd + (2 * cc + 1) * 512 + lane * 8]);
      const bf8 k1a = *(const bf8*)(&k_lds[kRd + (8 + 2 * cc) * 512 + lane * 8]);
      const bf8 k1b = *(const bf8*)(&k_lds[kRd + (8 + 2 * cc + 1) * 512 + lane * 8]);
      S0a = __builtin_amdgcn_mfma_f32_16x16x32_bf16(qf[2 * cc], k0a, S0a, 0, 0, 0);
      S0b = __builtin_amdgcn_mfma_f32_16x16x32_bf16(qf[2 * cc + 1], k0b, S0b, 0, 0, 0);
      S1a = __builtin_amdgcn_mfma_f32_16x16x32_bf16(qf[2 * cc], k1a, S1a, 0, 0, 0);
      S1b = __builtin_amdgcn_mfma_f32_16x16x32_bf16(qf[2 * cc + 1], k1b, S1b, 0, 0, 0);
    }
    const f4 S0 = S0a + S0b;
    const f4 S1 = S1a + S1b;

    // [C] PV(t-1): O += V(t-1)^T . P(t-1).  Compiler's vpre register-use wait
    // (vmcnt<=4) retires K(t+1) here -- the correctness anchor of the protocol.
    if (t > 0) {
      const int pprv = (((t & 1) ^ 1) << 11) + (((t & 1) ^ 1) << 9);  // *2560
      bf8 pb[4];
#pragma unroll
      for (int nq = 0; nq < 4; nq++)
        pb[nq] = *(const bf8*)(pB + pprv + (nq * 16 + l16) * 40 + quad * 8);
#pragma unroll
      for (int mi = 0; mi < 4; mi++)
#pragma unroll
        for (int nq = 0; nq < 4; nq++)
          Oacc[mi][nq] = __builtin_amdgcn_mfma_f32_16x16x32_bf16(
              vpre[mi], pb[nq], Oacc[mi][nq], 0, 0, 0);
    }

    // [D] V(t) loads (vpre regs free now; consumed at PV in step t+1)
#pragma unroll
    for (int mi = 0; mi < 4; mi++)
      vpre[mi] = *(const bf8*)(vsrc + (size_t)mi * 16384 + (size_t)t * 512);

    // [E] softmax of wave's 16q x 32kv -> p_lds[t&1]
    {
      const int pcur = ((t & 1) << 11) + ((t & 1) << 9);  // *2560
#pragma unroll
      for (int reg = 0; reg < 4; reg++) {
        const int qrow = wid * 16 + quad * 4 + reg;
        const float p0 = exp2f(S0[reg]);
        const float p1 = exp2f(S1[reg]);
        lpart[reg] += p0 + p1;
        union { float f; uint32_t u; } c0, c1;
        c0.f = p0; c1.f = p1;
        pB[pcur + qrow * 40 + l16] = (short)((c0.u + 0x8000u) >> 16);
        pB[pcur + qrow * 40 + 16 + l16] = (short)((c1.u + 0x8000u) >> 16);
      }
    }

    // [F] barrier WITHOUT vmem drain: own ds ops flushed, then sync.
    asm volatile("s_waitcnt lgkmcnt(0)" ::: "memory");
    __builtin_amdgcn_s_barrier();
    __builtin_amdgcn_sched_barrier(0);

    kRd += 8192;  if (kRd == 24576) kRd = 0;
    kPre += 8192; if (kPre == 24576) kPre = 0;
  }

  // ---- drain: PV(31) from p_lds[1] + vpre = V(31)
  {
    bf8 pb[4];
#pragma unroll
    for (int nq = 0; nq < 4; nq++)
      pb[nq] = *(const bf8*)(pB + 2560 + (nq * 16 + l16) * 40 + quad * 8);
#pragma unroll
    for (int mi = 0; mi < 4; mi++)
#pragma unroll
      for (int nq = 0; nq < 4; nq++)
        Oacc[mi][nq] = __builtin_amdgcn_mfma_f32_16x16x32_bf16(
            vpre[mi], pb[nq], Oacc[mi][nq], 0, 0, 0);
  }

  // ---- final l: reduce over 16 kv-col lanes (each q owned by one wave)
#pragma unroll
  for (int reg = 0; reg < 4; reg++) {
    float v = lpart[reg];
    v += __shfl_xor(v, 1, 64);
    v += __shfl_xor(v, 2, 64);
    v += __shfl_xor(v, 4, 64);
    v += __shfl_xor(v, 8, 64);
    if (l16 == 0) l_sh[wid * 16 + quad * 4 + reg] = v;
  }
  __syncthreads();

  // ---- epilogue: O^T[d][q] / l(q) -> o_ws [B,S,H*256]
  const int b = bh >> 3, h = bh & 7;
#pragma unroll
  for (int nq = 0; nq < 4; nq++) {
    const int q = nq * 16 + l16;
    const float inv = 1.f / l_sh[q];
    const size_t base = ((size_t)b * SEQ + qt * 64 + q) * (NH * DM) + h * DM + wid * 64;
#pragma unroll
    for (int mi = 0; mi < 4; mi++) {
      short4 s4;
      s4.x = (short)f2bf(Oacc[mi][nq][0] * inv);
      s4.y = (short)f2bf(Oacc[mi][nq][1] * inv);
      s4.z = (short)f2bf(Oacc[mi][nq][2] * inv);
      s4.w = (short)f2bf(Oacc[mi][nq][3] * inv);
      *(short4*)(o_ws + base + mi * 16 + quad * 4) = s4;
    }
  }
}

// ---------------------------------------------------------------------------
// Kernel 3: output projection.  BM=32, BN=64, BK=128, grid (128,4).  (unchanged)
// ---------------------------------------------------------------------------
__global__ __launch_bounds__(256) void outproj_kernel(
    const unsigned short* __restrict__ o_ws, const unsigned short* __restrict__ WoT,
    const float* __restrict__ bo, float* __restrict__ out) {
  __shared__ short a_lds[32][136];
  __shared__ short b_lds[64][136];

  const int tid = threadIdx.x;
  const int wid = tid >> 6, lane = tid & 63;
  const int quad = lane >> 4, l16 = lane & 15;
  const int wm = wid & 1, wn = wid >> 1;
  const int m0 = blockIdx.x * 32, n0 = blockIdx.y * 64;

  const f4 z4 = {0.f, 0.f, 0.f, 0.f};
  f4 acc[2];
#pragma unroll
  for (int i = 0; i < 2; i++) acc[i] = z4;

  const int ch = tid & 15, row = tid >> 4;
  for (int ko = 0; ko < 16; ko++) {
    const int k0 = ko * 128;
#pragma unroll
    for (int rb = 0; rb < 2; rb++) {
      int r = row + rb * 16;
      *(bf8*)(&a_lds[r][ch * 8]) = *(const bf8*)(o_ws + (size_t)(m0 + r) * 2048 + k0 + ch * 8);
    }
#pragma unroll
    for (int rb = 0; rb < 4; rb++) {
      int r = row + rb * 16;
      *(bf8*)(&b_lds[r][ch * 8]) = *(const bf8*)(WoT + (size_t)(n0 + r) * 2048 + k0 + ch * 8);
    }
    __syncthreads();
#pragma unroll
    for (int kc = 0; kc < 4; kc++) {
      const bf8 af = *(const bf8*)(&a_lds[wm * 16 + l16][kc * 32 + quad * 8]);
      bf8 bfv[2];
#pragma unroll
      for (int ni = 0; ni < 2; ni++)
        bfv[ni] = *(const bf8*)(&b_lds[wn * 32 + ni * 16 + l16][kc * 32 + quad * 8]);
#pragma unroll
      for (int ni = 0; ni < 2; ni++)
        acc[ni] = __builtin_amdgcn_mfma_f32_16x16x32_bf16(af, bfv[ni], acc[ni], 0, 0, 0);
    }
    __syncthreads();
  }
#pragma unroll
  for (int ni = 0; ni < 2; ni++) {
    const int n = n0 + wn * 32 + ni * 16 + l16;
    const float bv = bo[n];
#pragma unroll
    for (int reg = 0; reg < 4; reg++) {
      const int m = m0 + wm * 16 + quad * 4 + reg;
      out[(size_t)m * DM + n] = acc[ni][reg] + bv;
    }
  }
}

// ---------------------------------------------------------------------------
extern "C" void kernel_launch(void* const* d_in, const int* in_sizes, int n_in,
                              void* d_out, int out_size, void* d_ws, size_t ws_size,
                              hipStream_t stream) {
  const float* Q  = (const float*)d_in[0];
  const float* K  = (const float*)d_in[1];
  const float* V  = (const float*)d_in[2];
  const float* Wq = (const float*)d_in[3];
  const float* bq = (const float*)d_in[4];
  const float* Wk = (const float*)d_in[5];
  const float* bk = (const float*)d_in[6];
  const float* Wv = (const float*)d_in[7];
  const float* bv = (const float*)d_in[8];
  const float* Wo = (const float*)d_in[9];
  const float* bo = (const float*)d_in[10];
  float* out = (float*)d_out;

  char* ws = (char*)d_ws;
  const size_t QS = (size_t)NB * NH * SEQ * DM * 2;  // 16 MiB each
  unsigned short* q_frag = (unsigned short*)(ws);
  unsigned short* k_frag = (unsigned short*)(ws + QS);
  unsigned short* v_frag = (unsigned short*)(ws + 2 * QS);
  unsigned short* o_ws   = (unsigned short*)(ws + 3 * QS);
  const size_t WT = (size_t)2048 * 256 * 2;  // 1 MiB each
  unsigned short* Wt3 = (unsigned short*)(ws + 4 * QS);           // 3 MiB
  unsigned short* WoT = (unsigned short*)(ws + 4 * QS + 3 * WT);  // 1 MiB
  // Xbf (6 MiB) aliases o_ws: proj reads it before attn overwrites o_ws.
  unsigned short* Xbf = o_ws;

  prep_kernel<<<dim3(1024, 7), 256, 0, stream>>>(Wq, Wk, Wv, Wo, Q, K, V,
                                                 Wt3, WoT, Xbf);
  proj_kernel<<<dim3(32, 16, 3), 256, 0, stream>>>(Xbf, Wt3, bq, bk, bv,
                                                   q_frag, k_frag, v_frag);
  attn_kernel<<<512, 256, 0, stream>>>(q_frag, k_frag, v_frag, o_ws);
  outproj_kernel<<<dim3(128, 4), 256, 0, stream>>>(o_ws, WoT, bo, out);
}